// Round 1
// baseline (187.842 us; speedup 1.0000x reference)
//
#include <hip/hip_runtime.h>
#include <math.h>

#define NS   8      // samples
#define CC   256    // input channels
#define PP   961    // H*W
#define MM   7688   // NS*PP nodes
#define HID  512
#define OUTC 256

// deg = 963 for b in {0,7}, 964 otherwise; dinv = deg^-0.5
__device__ __forceinline__ float dinv_of(int b) {
    return (b == 0 || b == NS - 1) ? 0.0322245515f : 0.0322078318f;
}

// K1: S1[b*CC+c] = sum_p x[b,c,p]   (x layout [N,C,H,W], (b,c) row contiguous)
__global__ void colsum_x(const float* __restrict__ x, float* __restrict__ S1) {
    int bc = blockIdx.x;               // b*256 + c
    const float* src = x + (size_t)bc * PP;
    float s = 0.f;
    for (int i = threadIdx.x; i < PP; i += 256) s += src[i];
    __shared__ float red[256];
    red[threadIdx.x] = s;
    __syncthreads();
    for (int off = 128; off > 0; off >>= 1) {
        if (threadIdx.x < off) red[threadIdx.x] += red[threadIdx.x + off];
        __syncthreads();
    }
    if (threadIdx.x == 0) S1[bc] = red[0];
}

// K2: G1[(b*PP+p)*CC + c] = db^2*(S1[b,c] + x[b,c,p]) + db*(dm*x[b-1,c,p] + dp*x[b+1,c,p])
// 32x32 LDS tile transpose: read coalesced over p, write coalesced over c.
__global__ void build_g1(const float* __restrict__ x, const float* __restrict__ S1,
                         float* __restrict__ G1) {
    int pt = blockIdx.x, ct = blockIdx.y, b = blockIdx.z;
    int p0 = pt * 32, c0 = ct * 32;
    float db  = dinv_of(b);
    float wm  = (b > 0)      ? db * dinv_of(b - 1) : 0.f;
    float wp  = (b < NS - 1) ? db * dinv_of(b + 1) : 0.f;
    float db2 = db * db;
    __shared__ float t[32][33];
    int j = threadIdx.x & 31, i0 = threadIdx.x >> 5;
    int p = p0 + j;
    bool pv = (p < PP);
    #pragma unroll
    for (int r = 0; r < 4; ++r) {
        int i = i0 + r * 8;
        int c = c0 + i;
        float v = 0.f;
        if (pv) {
            size_t base = ((size_t)b * CC + c) * PP + p;
            float xb = x[base];
            float xm = (b > 0)      ? x[base - (size_t)CC * PP] : 0.f;
            float xp = (b < NS - 1) ? x[base + (size_t)CC * PP] : 0.f;
            v = db2 * (S1[b * CC + c] + xb) + wm * xm + wp * xp;
        }
        t[i][j] = v;
    }
    __syncthreads();
    int ii = threadIdx.x & 31, jj0 = threadIdx.x >> 5;
    #pragma unroll
    for (int r = 0; r < 4; ++r) {
        int jj = jj0 + r * 8;
        int pw = p0 + jj;
        if (pw < PP)
            G1[((size_t)b * PP + pw) * CC + c0 + ii] = t[ii][jj];
    }
}

// K3/K6: C[m,n] = leaky_relu( sum_k A[m,k]*Wt[n,k] + bias[n] )
// BM=BN=64, BK=16, 256 threads, 4x4 per thread.
template<int KD>
__global__ __launch_bounds__(256) void gemm_bias_lrelu(
    const float* __restrict__ A,    // [M, KD] row-major
    const float* __restrict__ Wt,   // [Nc, KD] row-major (torch Linear layout)
    const float* __restrict__ bias, // [Nc]
    float* __restrict__ C,          // [M, Nc]
    int M, int Nc)
{
    __shared__ __align__(16) float As[16][68];
    __shared__ __align__(16) float Bs[16][68];
    int tid = threadIdx.x;
    int m0 = blockIdx.x * 64, n0 = blockIdx.y * 64;
    int lr = tid >> 2, lc4 = (tid & 3) * 4;   // load: row 0..63, k-offset {0,4,8,12}
    int tx = tid & 15, ty = tid >> 4;
    float acc[4][4] = {};
    const float* Arow = A  + (size_t)(m0 + lr) * KD + lc4;
    const float* Brow = Wt + (size_t)(n0 + lr) * KD + lc4;
    bool am = (m0 + lr) < M;
    for (int kk = 0; kk < KD; kk += 16) {
        float4 av = am ? *(const float4*)(Arow + kk) : make_float4(0.f, 0.f, 0.f, 0.f);
        float4 bv = *(const float4*)(Brow + kk);
        __syncthreads();
        As[lc4 + 0][lr] = av.x; As[lc4 + 1][lr] = av.y;
        As[lc4 + 2][lr] = av.z; As[lc4 + 3][lr] = av.w;
        Bs[lc4 + 0][lr] = bv.x; Bs[lc4 + 1][lr] = bv.y;
        Bs[lc4 + 2][lr] = bv.z; Bs[lc4 + 3][lr] = bv.w;
        __syncthreads();
        #pragma unroll
        for (int k = 0; k < 16; ++k) {
            const float4 a = *(const float4*)(&As[k][ty * 4]);
            const float4 b = *(const float4*)(&Bs[k][tx * 4]);
            float ar[4] = {a.x, a.y, a.z, a.w};
            float br[4] = {b.x, b.y, b.z, b.w};
            #pragma unroll
            for (int i = 0; i < 4; ++i)
                #pragma unroll
                for (int jv = 0; jv < 4; ++jv)
                    acc[i][jv] = fmaf(ar[i], br[jv], acc[i][jv]);
        }
    }
    #pragma unroll
    for (int i = 0; i < 4; ++i) {
        int m = m0 + ty * 4 + i;
        if (m < M) {
            #pragma unroll
            for (int jv = 0; jv < 4; ++jv) {
                int n = n0 + tx * 4 + jv;
                float v = acc[i][jv] + bias[n];
                C[(size_t)m * Nc + n] = (v >= 0.f) ? v : 0.01f * v;
            }
        }
    }
}

// K4: partial column sums of H1 over p (split 8-way for parallelism)
__global__ void colsum_h1(const float* __restrict__ H1, float* __restrict__ S2p) {
    int ht = blockIdx.x, ps = blockIdx.y, b = blockIdx.z;
    int h = ht * 256 + threadIdx.x;
    int pbeg = ps * 121;
    int pend = pbeg + 121; if (pend > PP) pend = PP;
    float s = 0.f;
    for (int p = pbeg; p < pend; ++p)
        s += H1[((size_t)b * PP + p) * HID + h];
    S2p[((size_t)b * 8 + ps) * HID + h] = s;
}

// K4b: combine the 8 partials
__global__ void sum_s2p(const float* __restrict__ S2p, float* __restrict__ S2) {
    int i = blockIdx.x * 256 + threadIdx.x;   // < 4096
    int b = i >> 9, h = i & 511;
    float s = 0.f;
    #pragma unroll
    for (int ps = 0; ps < 8; ++ps) s += S2p[((size_t)b * 8 + ps) * HID + h];
    S2[i] = s;
}

// K5: weight-apply on H1 (same layout in/out, fully coalesced)
__global__ void build_g2(const float* __restrict__ H1, const float* __restrict__ S2,
                         float* __restrict__ G2) {
    int id = blockIdx.x * 256 + threadIdx.x;   // < MM*HID = 3,936,256
    int m = id >> 9;
    int h = id & 511;
    int b = m / PP;
    float db = dinv_of(b);
    float v = db * (S2[b * HID + h] + H1[id]);
    if (b > 0)      v += dinv_of(b - 1) * H1[id - PP * HID];
    if (b < NS - 1) v += dinv_of(b + 1) * H1[id + PP * HID];
    G2[id] = db * v;
}

// K7: out[o*PP + p] = max_b H2[(b*PP+p)*OUTC + o]   (32x32 tile transpose)
__global__ void max_out(const float* __restrict__ H2, float* __restrict__ out) {
    int pt = blockIdx.x, ot = blockIdx.y;
    int p0 = pt * 32, o0 = ot * 32;
    __shared__ float t[32][33];
    int i = threadIdx.x & 31, j0 = threadIdx.x >> 5;
    #pragma unroll
    for (int r = 0; r < 4; ++r) {
        int j = j0 + r * 8;
        int p = p0 + j;
        float v = -INFINITY;
        if (p < PP) {
            #pragma unroll
            for (int b = 0; b < NS; ++b)
                v = fmaxf(v, H2[((size_t)b * PP + p) * OUTC + o0 + i]);
        }
        t[j][i] = v;
    }
    __syncthreads();
    int jj = threadIdx.x & 31, ii0 = threadIdx.x >> 5;
    #pragma unroll
    for (int r = 0; r < 4; ++r) {
        int ii = ii0 + r * 8;
        int pw = p0 + jj;
        if (pw < PP)
            out[(size_t)(o0 + ii) * PP + pw] = t[jj][ii];
    }
}

extern "C" void kernel_launch(void* const* d_in, const int* in_sizes, int n_in,
                              void* d_out, int out_size, void* d_ws, size_t ws_size,
                              hipStream_t stream) {
    const float* x  = (const float*)d_in[0];
    const float* W1 = (const float*)d_in[1];
    const float* b1 = (const float*)d_in[2];
    const float* W2 = (const float*)d_in[3];
    const float* b2 = (const float*)d_in[4];
    float* out = (float*)d_out;
    float* ws  = (float*)d_ws;

    // workspace layout (floats); H2 aliases G1 (G1 dead after GEMM1)
    float* S1  = ws;                 //    2048
    float* S2p = ws + 2048;          //   32768
    float* S2  = ws + 34816;         //    4096
    float* G1  = ws + 38912;         // 1968128
    float* H1  = ws + 2007040;       // 3936256
    float* G2  = ws + 5943296;       // 3936256  -> total 9,879,552 floats = 39.5 MB
    float* H2  = G1;

    colsum_x<<<NS * CC, 256, 0, stream>>>(x, S1);
    build_g1<<<dim3(31, 8, NS), 256, 0, stream>>>(x, S1, G1);
    gemm_bias_lrelu<CC><<<dim3(121, HID / 64), 256, 0, stream>>>(G1, W1, b1, H1, MM, HID);
    colsum_h1<<<dim3(2, 8, NS), 256, 0, stream>>>(H1, S2p);
    sum_s2p<<<16, 256, 0, stream>>>(S2p, S2);
    build_g2<<<MM * HID / 256, 256, 0, stream>>>(H1, S2, G2);
    gemm_bias_lrelu<HID><<<dim3(121, OUTC / 64), 256, 0, stream>>>(G2, W2, b2, H2, MM, OUTC);
    max_out<<<dim3(31, 8), 256, 0, stream>>>(H2, out);
}

// Round 2
// 144.373 us; speedup vs baseline: 1.3011x; 1.3011x over previous
//
#include <hip/hip_runtime.h>
#include <math.h>

#define NS   8      // samples
#define CC   256    // input channels
#define PP   961    // H*W
#define MM   7688   // NS*PP nodes
#define MP   7744   // MM padded to 64
#define HID  512
#define OUTC 256

typedef _Float16 h16;
using half8  = __attribute__((ext_vector_type(8))) _Float16;
using floatx4 = __attribute__((ext_vector_type(4))) float;

#define AS1 __attribute__((address_space(1)))
#define AS3 __attribute__((address_space(3)))

// deg = 963 for b in {0,7}, 964 otherwise; dinv = deg^-0.5
__device__ __forceinline__ float dinv_of(int b) {
    return (b == 0 || b == NS - 1) ? 0.0322245515f : 0.0322078318f;
}

// K0: convert W1 (512x256) and W2 (256x512) fp32 -> fp16
__global__ void convert_w(const float* __restrict__ W1, const float* __restrict__ W2,
                          h16* __restrict__ w1h, h16* __restrict__ w2h) {
    int i = blockIdx.x * 256 + threadIdx.x;   // < 131072 per matrix; grid 1024 covers both
    if (i < HID * CC) w1h[i] = (h16)W1[i];
    int j = i - HID * CC;
    if (j >= 0 && j < OUTC * HID) w2h[j] = (h16)W2[j];
}

// K0b: zero the padded rows of G1 [7688..7743]x256 and G2 [7688..7743]x512
__global__ void zero_pad(h16* __restrict__ G1, h16* __restrict__ G2) {
    int i = blockIdx.x * 256 + threadIdx.x;   // < 43008
    if (i < 56 * CC) G1[(size_t)MM * CC + i] = (h16)0.f;
    else if (i < 56 * CC + 56 * HID) G2[(size_t)MM * HID + (i - 56 * CC)] = (h16)0.f;
}

// K1: S1[b*CC+c] = sum_p x[b,c,p]
__global__ void colsum_x(const float* __restrict__ x, float* __restrict__ S1) {
    int bc = blockIdx.x;
    const float* src = x + (size_t)bc * PP;
    float s = 0.f;
    for (int i = threadIdx.x; i < PP; i += 256) s += src[i];
    __shared__ float red[256];
    red[threadIdx.x] = s;
    __syncthreads();
    for (int off = 128; off > 0; off >>= 1) {
        if (threadIdx.x < off) red[threadIdx.x] += red[threadIdx.x + off];
        __syncthreads();
    }
    if (threadIdx.x == 0) S1[bc] = red[0];
}

// K2: G1[(b*PP+p)*CC + c] = db^2*(S1[b,c] + x[b,c,p]) + db*(d(b-1)*x[b-1,c,p] + d(b+1)*x[b+1,c,p])
// 32x32 LDS tile transpose; output fp16.
__global__ void build_g1(const float* __restrict__ x, const float* __restrict__ S1,
                         h16* __restrict__ G1) {
    int pt = blockIdx.x, ct = blockIdx.y, b = blockIdx.z;
    int p0 = pt * 32, c0 = ct * 32;
    float db  = dinv_of(b);
    float wm  = (b > 0)      ? db * dinv_of(b - 1) : 0.f;
    float wp  = (b < NS - 1) ? db * dinv_of(b + 1) : 0.f;
    float db2 = db * db;
    __shared__ float t[32][33];
    int j = threadIdx.x & 31, i0 = threadIdx.x >> 5;
    int p = p0 + j;
    bool pv = (p < PP);
    #pragma unroll
    for (int r = 0; r < 4; ++r) {
        int i = i0 + r * 8;
        int c = c0 + i;
        float v = 0.f;
        if (pv) {
            size_t base = ((size_t)b * CC + c) * PP + p;
            float xb = x[base];
            float xm = (b > 0)      ? x[base - (size_t)CC * PP] : 0.f;
            float xp = (b < NS - 1) ? x[base + (size_t)CC * PP] : 0.f;
            v = db2 * (S1[b * CC + c] + xb) + wm * xm + wp * xp;
        }
        t[i][j] = v;
    }
    __syncthreads();
    int ii = threadIdx.x & 31, jj0 = threadIdx.x >> 5;
    #pragma unroll
    for (int r = 0; r < 4; ++r) {
        int jj = jj0 + r * 8;
        int pw = p0 + jj;
        if (pw < PP)
            G1[((size_t)b * PP + pw) * CC + c0 + ii] = (h16)t[ii][jj];
    }
}

// K3/K6: MFMA GEMM. C[m,n] = lrelu( sum_k A[m,k]*B[n,k] + bias[n] ), fp16 in / fp32 out.
// 64x64 tile, BK=32, 256 threads = 4 waves; wave w owns n-cols [w*16, w*16+16).
template<int KD>
__global__ __launch_bounds__(256) void mfma_gemm(
    const h16* __restrict__ A,    // [MP][KD]
    const h16* __restrict__ B,    // [Nc][KD]  (torch Linear layout)
    const float* __restrict__ bias,
    float* __restrict__ C,        // [M][Nc] fp32
    int M, int Nc)
{
    __shared__ h16 As[64 * 32];
    __shared__ h16 Bs[64 * 32];
    int tid = threadIdx.x;
    int wave = tid >> 6, lane = tid & 63;
    int m0 = blockIdx.x * 64, n0 = blockIdx.y * 64;
    // staging: lane l of wave w covers row w*16+(l>>2), k-cols (l&3)*8..+8 (16B)
    int srow = wave * 16 + (lane >> 2);
    int scol = (lane & 3) * 8;
    const h16* ga = A + (size_t)(m0 + srow) * KD + scol;
    const h16* gb = B + (size_t)(n0 + srow) * KD + scol;
    h16* lva = &As[wave * 512];   // wave-uniform LDS base (lane*16B appended by HW)
    h16* lvb = &Bs[wave * 512];
    int fr = lane & 15;           // m-or-n within 16x16 tile
    int fq = lane >> 4;           // quad -> k-offset fq*8 (inputs), row fq*4 (output)
    floatx4 acc[4] = {{0.f,0.f,0.f,0.f},{0.f,0.f,0.f,0.f},{0.f,0.f,0.f,0.f},{0.f,0.f,0.f,0.f}};
    for (int kk = 0; kk < KD; kk += 32) {
        __builtin_amdgcn_global_load_lds((const AS1 void*)(const void*)(ga + kk),
                                         (AS3 void*)(void*)lva, 16, 0, 0);
        __builtin_amdgcn_global_load_lds((const AS1 void*)(const void*)(gb + kk),
                                         (AS3 void*)(void*)lvb, 16, 0, 0);
        __syncthreads();
        half8 bf = *(const half8*)&Bs[(wave * 16 + fr) * 32 + fq * 8];
        #pragma unroll
        for (int mb = 0; mb < 4; ++mb) {
            half8 af = *(const half8*)&As[(mb * 16 + fr) * 32 + fq * 8];
            acc[mb] = __builtin_amdgcn_mfma_f32_16x16x32_f16(af, bf, acc[mb], 0, 0, 0);
        }
        __syncthreads();
    }
    int col = n0 + wave * 16 + fr;
    float bv = bias[col];
    #pragma unroll
    for (int mb = 0; mb < 4; ++mb) {
        #pragma unroll
        for (int r = 0; r < 4; ++r) {
            int m = m0 + mb * 16 + fq * 4 + r;
            if (m < M) {
                float v = acc[mb][r] + bv;
                C[(size_t)m * Nc + col] = (v >= 0.f) ? v : 0.01f * v;
            }
        }
    }
}

// K4: partial column sums of H1 over p (8-way split)
__global__ void colsum_h1(const float* __restrict__ H1, float* __restrict__ S2p) {
    int ht = blockIdx.x, ps = blockIdx.y, b = blockIdx.z;
    int h = ht * 256 + threadIdx.x;
    int pbeg = ps * 121;
    int pend = pbeg + 121; if (pend > PP) pend = PP;
    float s = 0.f;
    for (int p = pbeg; p < pend; ++p)
        s += H1[((size_t)b * PP + p) * HID + h];
    S2p[((size_t)b * 8 + ps) * HID + h] = s;
}

// K4b: combine partials
__global__ void sum_s2p(const float* __restrict__ S2p, float* __restrict__ S2) {
    int i = blockIdx.x * 256 + threadIdx.x;   // < 4096
    int b = i >> 9, h = i & 511;
    float s = 0.f;
    #pragma unroll
    for (int ps = 0; ps < 8; ++ps) s += S2p[((size_t)b * 8 + ps) * HID + h];
    S2[i] = s;
}

// K5: weight-apply on H1 -> G2 (fp16), coalesced
__global__ void build_g2(const float* __restrict__ H1, const float* __restrict__ S2,
                         h16* __restrict__ G2) {
    int id = blockIdx.x * 256 + threadIdx.x;   // < MM*HID
    int m = id >> 9;
    int h = id & 511;
    int b = m / PP;
    float db = dinv_of(b);
    float v = db * (S2[b * HID + h] + H1[id]);
    if (b > 0)      v += dinv_of(b - 1) * H1[id - PP * HID];
    if (b < NS - 1) v += dinv_of(b + 1) * H1[id + PP * HID];
    G2[id] = (h16)(db * v);
}

// K7: out[o*PP + p] = max_b H2[(b*PP+p)*OUTC + o]
__global__ void max_out(const float* __restrict__ H2, float* __restrict__ out) {
    int pt = blockIdx.x, ot = blockIdx.y;
    int p0 = pt * 32, o0 = ot * 32;
    __shared__ float t[32][33];
    int i = threadIdx.x & 31, j0 = threadIdx.x >> 5;
    #pragma unroll
    for (int r = 0; r < 4; ++r) {
        int j = j0 + r * 8;
        int p = p0 + j;
        float v = -INFINITY;
        if (p < PP) {
            #pragma unroll
            for (int b = 0; b < NS; ++b)
                v = fmaxf(v, H2[((size_t)b * PP + p) * OUTC + o0 + i]);
        }
        t[j][i] = v;
    }
    __syncthreads();
    int jj = threadIdx.x & 31, ii0 = threadIdx.x >> 5;
    #pragma unroll
    for (int r = 0; r < 4; ++r) {
        int ii = ii0 + r * 8;
        int pw = p0 + jj;
        if (pw < PP)
            out[(size_t)(o0 + ii) * PP + pw] = t[jj][ii];
    }
}

extern "C" void kernel_launch(void* const* d_in, const int* in_sizes, int n_in,
                              void* d_out, int out_size, void* d_ws, size_t ws_size,
                              hipStream_t stream) {
    const float* x  = (const float*)d_in[0];
    const float* W1 = (const float*)d_in[1];
    const float* b1 = (const float*)d_in[2];
    const float* W2 = (const float*)d_in[3];
    const float* b2 = (const float*)d_in[4];
    float* out = (float*)d_out;
    float* ws  = (float*)d_ws;

    // workspace layout (float-offset units; all 16B aligned)
    float* S1   = ws;                       //    2,048 f
    float* S2p  = ws + 2048;                //   32,768 f
    float* S2   = ws + 34816;               //    4,096 f
    h16*  w1h   = (h16*)(ws + 38912);       //  131,072 h = 65,536 f
    h16*  w2h   = (h16*)(ws + 104448);      //  131,072 h
    h16*  G1    = (h16*)(ws + 169984);      //  MP*256 h = 991,232 f
    h16*  G2    = (h16*)(ws + 1161216);     //  MP*512 h = 1,982,464 f
    float* H1   = ws + 3143680;             //  MM*512 f = 3,936,256 f
    float* H2   = ws + 7079936;             //  MM*256 f = 1,968,128 f -> end 9,048,064 f (36.2 MB)

    convert_w<<<1024, 256, 0, stream>>>(W1, W2, w1h, w2h);
    colsum_x<<<NS * CC, 256, 0, stream>>>(x, S1);
    zero_pad<<<168, 256, 0, stream>>>(G1, G2);
    build_g1<<<dim3(31, 8, NS), 256, 0, stream>>>(x, S1, G1);
    mfma_gemm<CC><<<dim3(MP / 64, HID / 64), 256, 0, stream>>>(G1, w1h, b1, H1, MM, HID);
    colsum_h1<<<dim3(2, 8, NS), 256, 0, stream>>>(H1, S2p);
    sum_s2p<<<16, 256, 0, stream>>>(S2p, S2);
    build_g2<<<MM * HID / 256, 256, 0, stream>>>(H1, S2, G2);
    mfma_gemm<HID><<<dim3(MP / 64, OUTC / 64), 256, 0, stream>>>(G2, w2h, b2, H2, MM, OUTC);
    max_out<<<dim3(31, 8), 256, 0, stream>>>(H2, out);
}

// Round 3
// 100.684 us; speedup vs baseline: 1.8657x; 1.4339x over previous
//
#include <hip/hip_runtime.h>
#include <math.h>

#define NS   8      // samples
#define CC   256    // input channels
#define PP   961    // H*W
#define MM   7688   // NS*PP nodes
#define MP   7744   // MM padded to 64
#define HID  512
#define OUTC 256

typedef _Float16 h16;
using half8   = __attribute__((ext_vector_type(8))) _Float16;
using floatx4 = __attribute__((ext_vector_type(4))) float;

#define AS1 __attribute__((address_space(1)))
#define AS3 __attribute__((address_space(3)))

// deg = 963 for b in {0,7}, 964 otherwise; dinv = deg^-0.5
__device__ __forceinline__ float dinv_of(int b) {
    return (b == 0 || b == NS - 1) ? 0.0322245515f : 0.0322078318f;
}

// K0 prep: blocks [0,256): convert W1/W2 -> fp16 (float4); [256,2304): colsum_x; [2304,2320): zero S2
__global__ void prep(const float* __restrict__ W1, const float* __restrict__ W2,
                     h16* __restrict__ w1h, h16* __restrict__ w2h,
                     const float* __restrict__ x, float* __restrict__ S1,
                     float* __restrict__ S2) {
    int blk = blockIdx.x, tid = threadIdx.x;
    if (blk < 256) {
        bool second = blk >= 128;
        const float* src = second ? W2 : W1;
        h16* dst = second ? w2h : w1h;
        int i = ((blk & 127) * 256 + tid) * 4;
        float4 v = *(const float4*)(src + i);
        dst[i + 0] = (h16)v.x; dst[i + 1] = (h16)v.y;
        dst[i + 2] = (h16)v.z; dst[i + 3] = (h16)v.w;
    } else if (blk < 2304) {
        int bc = blk - 256;                       // b*CC + c
        const float* src = x + (size_t)bc * PP;
        float s = 0.f;
        for (int i = tid; i < PP; i += 256) s += src[i];
        __shared__ float red[256];
        red[tid] = s;
        __syncthreads();
        for (int off = 128; off > 0; off >>= 1) {
            if (tid < off) red[tid] += red[tid + off];
            __syncthreads();
        }
        if (tid == 0) S1[bc] = red[0];
    } else {
        int i = (blk - 2304) * 256 + tid;         // < 4096
        S2[i] = 0.f;
    }
}

// K1: G1[(b*PP+p)*CC + c] = db^2*(S1[b,c] + x[b,c,p]) + db*(d(b-1)*x[b-1,c,p] + d(b+1)*x[b+1,c,p])
__global__ void build_g1(const float* __restrict__ x, const float* __restrict__ S1,
                         h16* __restrict__ G1) {
    int pt = blockIdx.x, ct = blockIdx.y, b = blockIdx.z;
    int p0 = pt * 32, c0 = ct * 32;
    float db  = dinv_of(b);
    float wm  = (b > 0)      ? db * dinv_of(b - 1) : 0.f;
    float wp  = (b < NS - 1) ? db * dinv_of(b + 1) : 0.f;
    float db2 = db * db;
    __shared__ float t[32][33];
    int j = threadIdx.x & 31, i0 = threadIdx.x >> 5;
    int p = p0 + j;
    bool pv = (p < PP);
    #pragma unroll
    for (int r = 0; r < 4; ++r) {
        int i = i0 + r * 8;
        int c = c0 + i;
        float v = 0.f;
        if (pv) {
            size_t base = ((size_t)b * CC + c) * PP + p;
            float xb = x[base];
            float xm = (b > 0)      ? x[base - (size_t)CC * PP] : 0.f;
            float xp = (b < NS - 1) ? x[base + (size_t)CC * PP] : 0.f;
            v = db2 * (S1[b * CC + c] + xb) + wm * xm + wp * xp;
        }
        t[i][j] = v;
    }
    __syncthreads();
    int ii = threadIdx.x & 31, jj0 = threadIdx.x >> 5;
    #pragma unroll
    for (int r = 0; r < 4; ++r) {
        int jj = jj0 + r * 8;
        int pw = p0 + jj;
        if (pw < PP)
            G1[((size_t)b * PP + pw) * CC + c0 + ii] = (h16)t[ii][jj];
    }
}

// K2/K4: MFMA GEMM, 64x64 tile, BK=64, XOR-swizzled LDS chunks, fp16 in / fp32 acc.
// Epilogue: lrelu(acc+bias) -> C; optionally per-sample column sums -> atomicAdd S2.
template<int KD, bool DO_SUM, typename OutT>
__global__ __launch_bounds__(256) void mfma_gemm(
    const h16* __restrict__ A,    // [MP][KD]
    const h16* __restrict__ B,    // [Nc][KD]  (torch Linear layout)
    const float* __restrict__ bias,
    OutT* __restrict__ C,         // [M][Nc]
    float* __restrict__ S2,       // [NS][Nc] (used when DO_SUM)
    int M, int Nc)
{
    __shared__ __align__(16) h16 As[64 * 64];
    __shared__ __align__(16) h16 Bs[64 * 64];
    int tid = threadIdx.x, wave = tid >> 6, lane = tid & 63;
    int m0 = blockIdx.x * 64, n0 = blockIdx.y * 64;
    // staging: per instr, 8 rows x 8 chunks(16B); lane l -> row +(l>>3), slot l&7,
    // fetches global chunk c = (l&7)^(l>>3) so LDS slot s of row r holds chunk s^(r&7).
    int sro = lane >> 3;
    int sch = (lane & 7) ^ sro;
    const h16* ga0 = A + (size_t)(m0 + wave * 16 + sro) * KD + sch * 8;
    const h16* gb0 = B + (size_t)(n0 + wave * 16 + sro) * KD + sch * 8;
    h16* la0 = &As[(wave * 16) * 64];
    h16* la1 = &As[(wave * 16 + 8) * 64];
    h16* lb0 = &Bs[(wave * 16) * 64];
    h16* lb1 = &Bs[(wave * 16 + 8) * 64];
    int fr = lane & 15, fq = lane >> 4;
    floatx4 acc[4] = {{0.f,0.f,0.f,0.f},{0.f,0.f,0.f,0.f},{0.f,0.f,0.f,0.f},{0.f,0.f,0.f,0.f}};
    for (int kk = 0; kk < KD; kk += 64) {
        __builtin_amdgcn_global_load_lds((const AS1 void*)(const void*)(ga0 + kk),
                                         (AS3 void*)(void*)la0, 16, 0, 0);
        __builtin_amdgcn_global_load_lds((const AS1 void*)(const void*)(ga0 + 8 * KD + kk),
                                         (AS3 void*)(void*)la1, 16, 0, 0);
        __builtin_amdgcn_global_load_lds((const AS1 void*)(const void*)(gb0 + kk),
                                         (AS3 void*)(void*)lb0, 16, 0, 0);
        __builtin_amdgcn_global_load_lds((const AS1 void*)(const void*)(gb0 + 8 * KD + kk),
                                         (AS3 void*)(void*)lb1, 16, 0, 0);
        __syncthreads();
        #pragma unroll
        for (int ks = 0; ks < 2; ++ks) {
            int slot = (ks * 4 + fq) ^ (fr & 7);
            half8 bf = *(const half8*)&Bs[(wave * 16 + fr) * 64 + slot * 8];
            #pragma unroll
            for (int mb = 0; mb < 4; ++mb) {
                half8 af = *(const half8*)&As[(mb * 16 + fr) * 64 + slot * 8];
                acc[mb] = __builtin_amdgcn_mfma_f32_16x16x32_f16(af, bf, acc[mb], 0, 0, 0);
            }
        }
        __syncthreads();
    }
    int col = n0 + wave * 16 + fr;
    float bv = bias[col];
    float s_lo = 0.f, s_hi = 0.f;
    int blo = m0 / 961;
    int mcut = (blo + 1) * 961;
    #pragma unroll
    for (int mb = 0; mb < 4; ++mb) {
        #pragma unroll
        for (int r = 0; r < 4; ++r) {
            int m = m0 + mb * 16 + fq * 4 + r;
            if (m < M) {
                float v = acc[mb][r] + bv;
                v = (v >= 0.f) ? v : 0.01f * v;
                C[(size_t)m * Nc + col] = (OutT)v;
                if (DO_SUM) { if (m < mcut) s_lo += v; else s_hi += v; }
            }
        }
    }
    if (DO_SUM) {
        // lanes fq=0..3 share `col`; reduce across lane bits 4,5 then one atomic
        s_lo += __shfl_xor(s_lo, 16);
        s_lo += __shfl_xor(s_lo, 32);
        s_hi += __shfl_xor(s_hi, 16);
        s_hi += __shfl_xor(s_hi, 32);
        if (fq == 0) {
            atomicAdd(&S2[blo * Nc + col], s_lo);
            int bhi = (m0 + 63) / 961;
            if (bhi != blo && bhi < NS) atomicAdd(&S2[bhi * Nc + col], s_hi);
        }
    }
}

// K3: G2[m,h] = db*( db*(S2[b,h] + H1[m,h]) + d(b-1)*H1[m-PP,h] + d(b+1)*H1[m+PP,h] ), fp16 I/O
__global__ void build_g2(const h16* __restrict__ H1, const float* __restrict__ S2,
                         h16* __restrict__ G2) {
    int id8 = blockIdx.x * 256 + threadIdx.x;   // < MM*HID/8 = 492032
    int m = id8 >> 6;
    int h0 = (id8 & 63) * 8;
    int b = m / PP;
    float db = dinv_of(b);
    float dm = (b > 0)      ? dinv_of(b - 1) : 0.f;
    float dp = (b < NS - 1) ? dinv_of(b + 1) : 0.f;
    size_t base = (size_t)m * HID + h0;
    half8 z = {(h16)0,(h16)0,(h16)0,(h16)0,(h16)0,(h16)0,(h16)0,(h16)0};
    half8 hb = *(const half8*)(H1 + base);
    half8 hm = (b > 0)      ? *(const half8*)(H1 + base - (size_t)PP * HID) : z;
    half8 hp = (b < NS - 1) ? *(const half8*)(H1 + base + (size_t)PP * HID) : z;
    half8 o;
    #pragma unroll
    for (int j = 0; j < 8; ++j) {
        float v = db * (S2[b * HID + h0 + j] + (float)hb[j])
                + dm * (float)hm[j] + dp * (float)hp[j];
        o[j] = (h16)(db * v);
    }
    *(half8*)(G2 + base) = o;
}

// K5: out[o*PP + p] = max_b H2[(b*PP+p)*OUTC + o]
__global__ void max_out(const float* __restrict__ H2, float* __restrict__ out) {
    int pt = blockIdx.x, ot = blockIdx.y;
    int p0 = pt * 32, o0 = ot * 32;
    __shared__ float t[32][33];
    int i = threadIdx.x & 31, j0 = threadIdx.x >> 5;
    #pragma unroll
    for (int r = 0; r < 4; ++r) {
        int j = j0 + r * 8;
        int p = p0 + j;
        float v = -INFINITY;
        if (p < PP) {
            #pragma unroll
            for (int b = 0; b < NS; ++b)
                v = fmaxf(v, H2[((size_t)b * PP + p) * OUTC + o0 + i]);
        }
        t[j][i] = v;
    }
    __syncthreads();
    int jj = threadIdx.x & 31, ii0 = threadIdx.x >> 5;
    #pragma unroll
    for (int r = 0; r < 4; ++r) {
        int ii = ii0 + r * 8;
        int pw = p0 + jj;
        if (pw < PP)
            out[(size_t)(o0 + ii) * PP + pw] = t[jj][ii];
    }
}

extern "C" void kernel_launch(void* const* d_in, const int* in_sizes, int n_in,
                              void* d_out, int out_size, void* d_ws, size_t ws_size,
                              hipStream_t stream) {
    const float* x  = (const float*)d_in[0];
    const float* W1 = (const float*)d_in[1];
    const float* b1 = (const float*)d_in[2];
    const float* W2 = (const float*)d_in[3];
    const float* b2 = (const float*)d_in[4];
    float* out = (float*)d_out;
    float* ws  = (float*)d_ws;

    // workspace layout (float offsets, all 16B-aligned)
    float* S1  = ws;                        //      2,048 f
    float* S2  = ws + 2048;                 //      4,096 f
    h16*  w1h  = (h16*)(ws + 6144);         //  131,072 h =  65,536 f
    h16*  w2h  = (h16*)(ws + 71680);        //  131,072 h
    h16*  G1   = (h16*)(ws + 137216);       //  MP*CC  h = 991,232 f
    h16*  H1   = (h16*)(ws + 1128448);      //  MM*HID h = 1,968,128 f
    h16*  G2   = (h16*)(ws + 3096576);      //  MP*HID h = 1,982,464 f
    float* H2  = ws + 5079040;              //  MM*OUTC f = 1,968,128 f -> end 7,047,168 f (28.2 MB)

    prep<<<2320, 256, 0, stream>>>(W1, W2, w1h, w2h, x, S1, S2);
    build_g1<<<dim3(31, 8, NS), 256, 0, stream>>>(x, S1, G1);
    mfma_gemm<CC, true, h16><<<dim3(MP / 64, HID / 64), 256, 0, stream>>>(
        G1, w1h, b1, H1, S2, MM, HID);
    build_g2<<<1922, 256, 0, stream>>>(H1, S2, G2);
    mfma_gemm<HID, false, float><<<dim3(MP / 64, OUTC / 64), 256, 0, stream>>>(
        G2, w2h, b2, H2, nullptr, MM, OUTC);
    max_out<<<dim3(31, 8), 256, 0, stream>>>(H2, out);
}

// Round 4
// 95.413 us; speedup vs baseline: 1.9687x; 1.0552x over previous
//
#include <hip/hip_runtime.h>
#include <math.h>

#define NS   8      // samples
#define CC   256    // input channels
#define PP   961    // H*W
#define MM   7688   // NS*PP nodes
#define MP   7744   // MM padded to 64
#define HID  512
#define OUTC 256

typedef _Float16 h16;
using half8   = __attribute__((ext_vector_type(8))) _Float16;
using floatx4 = __attribute__((ext_vector_type(4))) float;

#define AS1 __attribute__((address_space(1)))
#define AS3 __attribute__((address_space(3)))

// deg = 963 for b in {0,7}, 964 otherwise; dinv = deg^-0.5
__device__ __forceinline__ float dinv_of(int b) {
    return (b == 0 || b == NS - 1) ? 0.0322245515f : 0.0322078318f;
}

// K0 prep: [0,256): convert W1/W2 -> fp16; [256,2304): colsum_x -> S1; [2304,2312): zero SY
__global__ void prep(const float* __restrict__ W1, const float* __restrict__ W2,
                     h16* __restrict__ w1h, h16* __restrict__ w2h,
                     const float* __restrict__ x, float* __restrict__ S1,
                     float* __restrict__ SY) {
    int blk = blockIdx.x, tid = threadIdx.x;
    if (blk < 256) {
        bool second = blk >= 128;
        const float* src = second ? W2 : W1;
        h16* dst = second ? w2h : w1h;
        int i = ((blk & 127) * 256 + tid) * 4;
        float4 v = *(const float4*)(src + i);
        dst[i + 0] = (h16)v.x; dst[i + 1] = (h16)v.y;
        dst[i + 2] = (h16)v.z; dst[i + 3] = (h16)v.w;
    } else if (blk < 2304) {
        int bc = blk - 256;                       // b*CC + c
        const float* src = x + (size_t)bc * PP;
        float s = 0.f;
        for (int i = tid; i < PP; i += 256) s += src[i];
        __shared__ float red[256];
        red[tid] = s;
        __syncthreads();
        for (int off = 128; off > 0; off >>= 1) {
            if (tid < off) red[tid] += red[tid + off];
            __syncthreads();
        }
        if (tid == 0) S1[bc] = red[0];
    } else {
        int i = (blk - 2304) * 256 + tid;         // < 2048
        SY[i] = 0.f;
    }
}

// K1: G1[(b*PP+p)*CC + c] = db^2*(S1[b,c] + x[b,c,p]) + db*(d(b-1)*x[b-1,c,p] + d(b+1)*x[b+1,c,p])
__global__ void build_g1(const float* __restrict__ x, const float* __restrict__ S1,
                         h16* __restrict__ G1) {
    int pt = blockIdx.x, ct = blockIdx.y, b = blockIdx.z;
    int p0 = pt * 32, c0 = ct * 32;
    float db  = dinv_of(b);
    float wm  = (b > 0)      ? db * dinv_of(b - 1) : 0.f;
    float wp  = (b < NS - 1) ? db * dinv_of(b + 1) : 0.f;
    float db2 = db * db;
    __shared__ float t[32][33];
    int j = threadIdx.x & 31, i0 = threadIdx.x >> 5;
    int p = p0 + j;
    bool pv = (p < PP);
    #pragma unroll
    for (int r = 0; r < 4; ++r) {
        int i = i0 + r * 8;
        int c = c0 + i;
        float v = 0.f;
        if (pv) {
            size_t base = ((size_t)b * CC + c) * PP + p;
            float xb = x[base];
            float xm = (b > 0)      ? x[base - (size_t)CC * PP] : 0.f;
            float xp = (b < NS - 1) ? x[base + (size_t)CC * PP] : 0.f;
            v = db2 * (S1[b * CC + c] + xb) + wm * xm + wp * xp;
        }
        t[i][j] = v;
    }
    __syncthreads();
    int ii = threadIdx.x & 31, jj0 = threadIdx.x >> 5;
    #pragma unroll
    for (int r = 0; r < 4; ++r) {
        int jj = jj0 + r * 8;
        int pw = p0 + jj;
        if (pw < PP)
            G1[((size_t)b * PP + pw) * CC + c0 + ii] = (h16)t[ii][jj];
    }
}

// K2/K3: MFMA GEMM, 64x64 tile, BK=64, XOR-swizzled LDS chunks, fp16 in / fp32 acc.
// ACT: v = lrelu(acc + bias). DO_SUM: per-sample column sums of raw v -> atomicAdd SY.
template<int KD, bool ACT, bool DO_SUM, typename OutT>
__global__ __launch_bounds__(256) void mfma_gemm(
    const h16* __restrict__ A,    // [MP][KD]
    const h16* __restrict__ B,    // [Nc][KD]  (torch Linear layout)
    const float* __restrict__ bias,
    OutT* __restrict__ C,         // [M][Nc]
    float* __restrict__ SY,       // [NS][Nc] (used when DO_SUM)
    int M, int Nc)
{
    __shared__ __align__(16) h16 As[64 * 64];
    __shared__ __align__(16) h16 Bs[64 * 64];
    int tid = threadIdx.x, wave = tid >> 6, lane = tid & 63;
    int m0 = blockIdx.x * 64, n0 = blockIdx.y * 64;
    // staging: per instr, 8 rows x 8 chunks(16B); lane l -> row +(l>>3), slot l&7,
    // fetches global chunk c = (l&7)^(l>>3) so LDS slot s of row r holds chunk s^(r&7).
    int sro = lane >> 3;
    int sch = (lane & 7) ^ sro;
    const h16* ga0 = A + (size_t)(m0 + wave * 16 + sro) * KD + sch * 8;
    const h16* gb0 = B + (size_t)(n0 + wave * 16 + sro) * KD + sch * 8;
    h16* la0 = &As[(wave * 16) * 64];
    h16* la1 = &As[(wave * 16 + 8) * 64];
    h16* lb0 = &Bs[(wave * 16) * 64];
    h16* lb1 = &Bs[(wave * 16 + 8) * 64];
    int fr = lane & 15, fq = lane >> 4;
    floatx4 acc[4] = {{0.f,0.f,0.f,0.f},{0.f,0.f,0.f,0.f},{0.f,0.f,0.f,0.f},{0.f,0.f,0.f,0.f}};
    for (int kk = 0; kk < KD; kk += 64) {
        __builtin_amdgcn_global_load_lds((const AS1 void*)(const void*)(ga0 + kk),
                                         (AS3 void*)(void*)la0, 16, 0, 0);
        __builtin_amdgcn_global_load_lds((const AS1 void*)(const void*)(ga0 + 8 * KD + kk),
                                         (AS3 void*)(void*)la1, 16, 0, 0);
        __builtin_amdgcn_global_load_lds((const AS1 void*)(const void*)(gb0 + kk),
                                         (AS3 void*)(void*)lb0, 16, 0, 0);
        __builtin_amdgcn_global_load_lds((const AS1 void*)(const void*)(gb0 + 8 * KD + kk),
                                         (AS3 void*)(void*)lb1, 16, 0, 0);
        __syncthreads();
        #pragma unroll
        for (int ks = 0; ks < 2; ++ks) {
            int slot = (ks * 4 + fq) ^ (fr & 7);
            half8 bf = *(const half8*)&Bs[(wave * 16 + fr) * 64 + slot * 8];
            #pragma unroll
            for (int mb = 0; mb < 4; ++mb) {
                half8 af = *(const half8*)&As[(mb * 16 + fr) * 64 + slot * 8];
                acc[mb] = __builtin_amdgcn_mfma_f32_16x16x32_f16(af, bf, acc[mb], 0, 0, 0);
            }
        }
        __syncthreads();
    }
    int col = n0 + wave * 16 + fr;
    float bv = ACT ? bias[col] : 0.f;
    float s_lo = 0.f, s_hi = 0.f;
    int blo = m0 / 961;
    int mcut = (blo + 1) * 961;
    #pragma unroll
    for (int mb = 0; mb < 4; ++mb) {
        #pragma unroll
        for (int r = 0; r < 4; ++r) {
            int m = m0 + mb * 16 + fq * 4 + r;
            if (m < M) {
                float v = acc[mb][r] + bv;
                if (ACT) v = (v >= 0.f) ? v : 0.01f * v;
                C[(size_t)m * Nc + col] = (OutT)v;
                if (DO_SUM) { if (m < mcut) s_lo += v; else s_hi += v; }
            }
        }
    }
    if (DO_SUM) {
        s_lo += __shfl_xor(s_lo, 16);
        s_lo += __shfl_xor(s_lo, 32);
        s_hi += __shfl_xor(s_hi, 16);
        s_hi += __shfl_xor(s_hi, 32);
        if (fq == 0) {
            atomicAdd(&SY[blo * Nc + col], s_lo);
            int bhi = (m0 + 63) / 961;
            if (bhi != blo && bhi < NS) atomicAdd(&SY[bhi * Nc + col], s_hi);
        }
    }
}

// K4: out[o*PP+p] = max_b lrelu( b2[o] + db*( db*(SY[b,o]+Y[b,p,o]) + dm*Y[b-1,p,o] + dp*Y[b+1,p,o] ) )
__global__ void final_max(const float* __restrict__ Y, const float* __restrict__ SY,
                          const float* __restrict__ b2, float* __restrict__ out) {
    int pt = blockIdx.x, ot = blockIdx.y;
    int p0 = pt * 32, o0 = ot * 32;
    __shared__ float t[32][33];
    int i = threadIdx.x & 31, j0 = threadIdx.x >> 5;
    int o = o0 + i;
    float bias = b2[o];
    #pragma unroll
    for (int r = 0; r < 4; ++r) {
        int j = j0 + r * 8;
        int p = p0 + j;
        float vmax = -INFINITY;
        if (p < PP) {
            float y[NS];
            #pragma unroll
            for (int b = 0; b < NS; ++b)
                y[b] = Y[((size_t)b * PP + p) * OUTC + o];
            #pragma unroll
            for (int b = 0; b < NS; ++b) {
                float db = dinv_of(b);
                float a = db * (SY[b * OUTC + o] + y[b]);
                if (b > 0)      a += dinv_of(b - 1) * y[b - 1];
                if (b < NS - 1) a += dinv_of(b + 1) * y[b + 1];
                float z = db * a + bias;
                z = (z >= 0.f) ? z : 0.01f * z;
                vmax = fmaxf(vmax, z);
            }
        }
        t[j][i] = vmax;
    }
    __syncthreads();
    int jj = threadIdx.x & 31, ii0 = threadIdx.x >> 5;
    #pragma unroll
    for (int r = 0; r < 4; ++r) {
        int ii = ii0 + r * 8;
        int pw = p0 + jj;
        if (pw < PP)
            out[(size_t)(o0 + ii) * PP + pw] = t[jj][ii];
    }
}

extern "C" void kernel_launch(void* const* d_in, const int* in_sizes, int n_in,
                              void* d_out, int out_size, void* d_ws, size_t ws_size,
                              hipStream_t stream) {
    const float* x  = (const float*)d_in[0];
    const float* W1 = (const float*)d_in[1];
    const float* b1 = (const float*)d_in[2];
    const float* W2 = (const float*)d_in[3];
    const float* b2 = (const float*)d_in[4];
    float* out = (float*)d_out;
    float* ws  = (float*)d_ws;

    // workspace layout (float offsets, all 16B-aligned)
    float* S1  = ws;                        //      2,048 f
    float* SY  = ws + 2048;                 //      2,048 f (NS*OUTC)
    h16*  w1h  = (h16*)(ws + 4096);         //  131,072 h =  65,536 f
    h16*  w2h  = (h16*)(ws + 69632);        //  131,072 h
    h16*  G1   = (h16*)(ws + 135168);       //  MP*CC  h =  991,232 f
    h16*  H1   = (h16*)(ws + 1126400);      //  MP*HID h = 1,982,464 f (pad rows stay poison: finite)
    float* Y   = ws + 3108864;              //  MM*OUTC f = 1,968,128 f -> end 5,076,992 f (20.3 MB)

    prep<<<2312, 256, 0, stream>>>(W1, W2, w1h, w2h, x, S1, SY);
    build_g1<<<dim3(31, 8, NS), 256, 0, stream>>>(x, S1, G1);
    mfma_gemm<CC, true, false, h16><<<dim3(MP / 64, HID / 64), 256, 0, stream>>>(
        G1, w1h, b1, H1, nullptr, MM, HID);
    mfma_gemm<HID, false, true, float><<<dim3(MP / 64, OUTC / 64), 256, 0, stream>>>(
        H1, w2h, nullptr, Y, SY, MM, OUTC);
    final_max<<<dim3(31, 8), 256, 0, stream>>>(Y, SY, b2, out);
}